// Round 1
// 335.776 us; speedup vs baseline: 1.1181x; 1.1181x over previous
//
#include <hip/hip_runtime.h>

// Problem constants
#define HDIM 1024
#define SEQ  2048
#define BATCH 16
#define VOCAB 250002
#define M_TOT (BATCH * SEQ)                 // 32768 rows
#define SPARSE_OFF (BATCH * HDIM)           // 16384
#define COLBERT_OFF (SPARSE_OFF + BATCH * VOCAB)  // 4016416

typedef __attribute__((ext_vector_type(8))) short short8;   // 8 bf16 (4 VGPRs)
typedef __attribute__((ext_vector_type(4))) float f32x4;

static __device__ __forceinline__ unsigned short f2bf(float f) {
  union { float f; unsigned u; } v; v.f = f;
  unsigned r = v.u + 0x7fffu + ((v.u >> 16) & 1u);  // RNE
  return (unsigned short)(r >> 16);
}

// ---------------------------------------------------------------------------
// Kernel 1 (prep): blocks 0..1023 transpose+PACK W fp32(k,n) -> bf16 packed
// fragment-major Bp[(n16*32+kk)*512 + lane*8 + e]  (lane = q*16 + (n&15),
// k = kk*32 + q*8 + e)  so a wave's MFMA B-fragment load is one contiguous
// 1 KB global_load_dwordx4 from the L2-resident 2 MB buffer.
// blocks 1024..1535 zero the sparse output region; 1536..1551 dense head.
// ---------------------------------------------------------------------------
__global__ __launch_bounds__(256) void prep_kernel(
    const float* __restrict__ W, unsigned short* __restrict__ Wt,
    float* __restrict__ out, const float* __restrict__ hidden)
{
  __shared__ float tile[32][33];
  __shared__ float red[4];
  const int blk = blockIdx.x;
  if (blk < 1024) {
    // transpose (32x32 tile); block laid out as 256 = 32x8
    const int n0 = (blk & 31) * 32, k0 = (blk >> 5) * 32;
    const int tx = threadIdx.x & 31, ty = threadIdx.x >> 5;   // 32 x 8
#pragma unroll
    for (int i = ty; i < 32; i += 8)
      tile[i][tx] = W[(size_t)(k0 + i) * HDIM + n0 + tx];
    __syncthreads();
#pragma unroll
    for (int i = ty; i < 32; i += 8) {
      const int n = n0 + i, k = k0 + tx;
      const size_t idx = (size_t)((n >> 4) * 32 + (k >> 5)) * 512
                       + (size_t)((((k >> 3) & 3) * 16 + (n & 15)) * 8 + (k & 7));
      Wt[idx] = f2bf(tile[tx][i]);
    }
  } else if (blk < 1536) {
    // zero sparse region: 4000032 floats = 1000008 float4
    float4 z = {0.f, 0.f, 0.f, 0.f};
    float4* p = (float4*)(out + SPARSE_OFF);
    int idx = (blk - 1024) * 256 + threadIdx.x;
#pragma unroll 1
    for (; idx < 1000008; idx += 512 * 256) p[idx] = z;
  } else {
    // dense head: L2-normalize CLS row of batch b
    const int b = blk - 1536;
    const int t = threadIdx.x;
    const float4* x = (const float4*)(hidden + (size_t)b * SEQ * HDIM);
    float4 v = x[t];
    float ss = v.x * v.x + v.y * v.y + v.z * v.z + v.w * v.w;
#pragma unroll
    for (int off = 32; off; off >>= 1) ss += __shfl_down(ss, off);
    if ((t & 63) == 0) red[t >> 6] = ss;
    __syncthreads();
    float tot = red[0] + red[1] + red[2] + red[3];
    float inv = 1.0f / fmaxf(sqrtf(tot), 1e-12f);
    v.x *= inv; v.y *= inv; v.z *= inv; v.w *= inv;
    ((float4*)(out + (size_t)b * HDIM))[t] = v;
  }
}

// ---------------------------------------------------------------------------
// Kernel 2 (fused): per 64-row block:
//   prologue: read fp32 slab once (nontemporal), cast -> bf16 into swizzled
//             LDS (128 KB, layout [kk][row][slot-rotated 32k] ^ kk-bit XOR),
//             sparse dot + scatter-max as a side product. ONE barrier.
//   K-loop:   barrier-free. A frags via 4x ds_read_b128; B frags via 8x
//             contiguous 1 KB global loads from the packed L2-resident Wt.
//             Register ping-pong double-buffer (no LDS for B, no syncthreads,
//             no vmcnt(0) drain).
//   epilogue: bias, row ss reduce, mask+L2norm, nontemporal stores.
// ---------------------------------------------------------------------------
#define FUSED_LDS (64 * HDIM * 2 + (64 * 8 + 64) * 4)   // 131072 + 2304

__global__ __launch_bounds__(512, 2) void fused_kernel(
    const float* __restrict__ hidden,
    const unsigned short* __restrict__ Bp,   // packed (1024,1024) bf16
    const float* __restrict__ bias,          // (1024,)
    const float* __restrict__ mask,          // (B, S)
    const float* __restrict__ sparse_W,      // (1024,)
    const float* __restrict__ sparse_b,      // (1,)
    const int* __restrict__ input_ids,       // (B*S,)
    float* __restrict__ out)
{
  extern __shared__ __align__(16) char smem[];
  unsigned short* As = (unsigned short*)smem;            // 64x1024 bf16, swizzled
  float* redLDS = (float*)(smem + 64 * HDIM * 2);        // [64][8]
  float* invLDS = redLDS + 64 * 8;                       // [64]

  const int t = threadIdx.x;
  const int w = t >> 6, l = t & 63;
  const int q = l >> 4, ml = l & 15;
  const int mBase = blockIdx.x * 64;

  // ---- prologue: cast slab + sparse head. wave w owns rows w*8 .. w*8+7 ----
  {
    const float sb = sparse_b[0];
    for (int r8 = 0; r8 < 8; r8++) {
      const int row = w * 8 + r8;
      const int gm = mBase + row;
      const float* src = hidden + (size_t)gm * HDIM;
      float dot = 0.f;
#pragma unroll
      for (int c = 0; c < 2; c++) {
        const int k0 = c * 512 + l * 8;
        f32x4 x0 = __builtin_nontemporal_load((const f32x4*)(src + k0));
        f32x4 x1 = __builtin_nontemporal_load((const f32x4*)(src + k0) + 1);
        const f32x4 w0 = *((const f32x4*)(sparse_W + k0));
        const f32x4 w1 = *((const f32x4*)(sparse_W + k0) + 1);
        dot = fmaf(x0.x, w0.x, dot); dot = fmaf(x0.y, w0.y, dot);
        dot = fmaf(x0.z, w0.z, dot); dot = fmaf(x0.w, w0.w, dot);
        dot = fmaf(x1.x, w1.x, dot); dot = fmaf(x1.y, w1.y, dot);
        dot = fmaf(x1.z, w1.z, dot); dot = fmaf(x1.w, w1.w, dot);
        short8 o;
        o[0] = (short)f2bf(x0.x); o[1] = (short)f2bf(x0.y);
        o[2] = (short)f2bf(x0.z); o[3] = (short)f2bf(x0.w);
        o[4] = (short)f2bf(x1.x); o[5] = (short)f2bf(x1.y);
        o[6] = (short)f2bf(x1.z); o[7] = (short)f2bf(x1.w);
        // LDS layout: [kk][row][slot] with slot=(q+(row>>1))&3, then XOR
        // (kk&1)<<6 to spread banks across the kk dimension on writes.
        const int kk = k0 >> 5;
        const int slot = (((k0 >> 3) & 3) + (row >> 1)) & 3;
        const int byte = (kk * 4096 + row * 64 + slot * 16) ^ ((kk & 1) << 6);
        *(short8*)(smem + byte) = o;
      }
#pragma unroll
      for (int off = 32; off; off >>= 1) dot += __shfl_down(dot, off);
      if (l == 0) {
        const float wgt = dot + sb;
        if (wgt > 0.f) {
          const int id = input_ids[gm];
          if (id > 3) {                      // UNUSED_TOKEN_IDS = {0,1,2,3}
            const int b = gm >> 11;
            atomicMax((int*)(out + SPARSE_OFF + (size_t)b * VOCAB + id),
                      __float_as_int(wgt));
          }
        }
      }
    }
  }
  __syncthreads();

  // ---- K-loop: barrier-free, register-double-buffered ----
  int aoff[4];
#pragma unroll
  for (int i = 0; i < 4; i++) {
    const int ar = i * 16 + ml;
    aoff[i] = ar * 64 + (((q + (ar >> 1)) & 3) * 16);  // bytes (kk part added/XORed per step)
  }
  const unsigned short* Bpw = Bp + (size_t)(w * 8 * 32) * 512 + l * 8;

  f32x4 acc[4][8] = {};
  short8 aC[4], aN[4], b0[4], b1[4];

#define LOADA(dst, KK) do {                                              \
    const int fl_ = ((KK) & 1) << 6;                                     \
    const int kb_ = (KK) * 4096;                                         \
    _Pragma("unroll")                                                    \
    for (int i_ = 0; i_ < 4; i_++)                                       \
      dst[i_] = *(const short8*)(smem + ((aoff[i_] ^ fl_) + kb_));       \
  } while (0)

#define LOADB(dst, JOFS, KK) do {                                        \
    _Pragma("unroll")                                                    \
    for (int j_ = 0; j_ < 4; j_++)                                       \
      dst[j_] = *(const short8*)(Bpw +                                   \
          (size_t)(((j_ + (JOFS)) * 32 + (KK)) * 512));                  \
  } while (0)

#define MF(AF, BF, JB) do {                                              \
    _Pragma("unroll")                                                    \
    for (int i_ = 0; i_ < 4; i_++)                                       \
      _Pragma("unroll")                                                  \
      for (int j_ = 0; j_ < 4; j_++)                                     \
        acc[i_][(JB) + j_] = __builtin_amdgcn_mfma_f32_16x16x32_bf16(    \
            AF[i_], BF[j_], acc[i_][(JB) + j_], 0, 0, 0);                \
  } while (0)

  LOADA(aC, 0);
  LOADB(b0, 0, 0);

#pragma unroll 1
  for (int kk = 0; kk < 32; kk += 2) {
    // even step: consume aC/b0, prefetch for kk+1
    LOADB(b1, 4, kk);
    LOADA(aN, kk + 1);
    MF(aC, b0, 0);
    LOADB(b0, 0, kk + 1);
    MF(aC, b1, 4);
    // odd step: consume aN/b0, prefetch for kk+2 (wrap harmless at end)
    const int k2 = (kk + 2) & 31;
    LOADB(b1, 4, kk + 1);
    LOADA(aC, k2);
    MF(aN, b0, 0);
    LOADB(b0, 0, k2);
    MF(aN, b1, 4);
  }

  // ---- epilogue: bias, row sum-of-squares, mask+norm, write ----
  float bv[8];
#pragma unroll
  for (int j = 0; j < 8; j++) bv[j] = bias[w * 128 + j * 16 + ml];
#pragma unroll
  for (int i = 0; i < 4; i++)
#pragma unroll
    for (int j = 0; j < 8; j++)
#pragma unroll
      for (int r = 0; r < 4; r++) acc[i][j][r] += bv[j];

  // per-row partial ss over this wave's 128 cols; reduce across 16 ml lanes
#pragma unroll
  for (int i = 0; i < 4; i++) {
#pragma unroll
    for (int r = 0; r < 4; r++) {
      float ss = 0.0f;
#pragma unroll
      for (int j = 0; j < 8; j++) { float x = acc[i][j][r]; ss = fmaf(x, x, ss); }
      ss += __shfl_xor(ss, 1); ss += __shfl_xor(ss, 2);
      ss += __shfl_xor(ss, 4); ss += __shfl_xor(ss, 8);
      if (ml == 0) redLDS[(i * 16 + q * 4 + r) * 8 + w] = ss;
    }
  }
  __syncthreads();

  {
    const int row = t >> 3, wp = t & 7;   // 512 threads -> 64 rows x 8 partials
    float v = redLDS[row * 8 + wp];
    v += __shfl_xor(v, 1); v += __shfl_xor(v, 2); v += __shfl_xor(v, 4);
    if (wp == 0) {
      const int gm = mBase + row;
      const int s = gm & (SEQ - 1), b = gm >> 11;
      const float mval = mask[b * SEQ + s];
      // x*mval / max(|mval|*||x||, eps)
      invLDS[row] = mval / fmaxf(fabsf(mval) * sqrtf(v), 1e-12f);
    }
  }
  __syncthreads();

#pragma unroll
  for (int i = 0; i < 4; i++) {
#pragma unroll
    for (int r = 0; r < 4; r++) {
      const int row = i * 16 + q * 4 + r;
      const int gm = mBase + row;
      const int s = gm & (SEQ - 1);
      if (s != 0) {
        const int b = gm >> 11;
        float* orow = out + COLBERT_OFF + (size_t)(b * (SEQ - 1) + s - 1) * HDIM;
        const float iv = invLDS[row];
#pragma unroll
        for (int j = 0; j < 8; j++)
          __builtin_nontemporal_store(acc[i][j][r] * iv,
                                      orow + w * 128 + j * 16 + ml);
      }
    }
  }
}

// ---------------------------------------------------------------------------
extern "C" void kernel_launch(void* const* d_in, const int* in_sizes, int n_in,
                              void* d_out, int out_size, void* d_ws, size_t ws_size,
                              hipStream_t stream) {
  (void)in_sizes; (void)n_in; (void)out_size; (void)ws_size;
  const float* hidden = (const float*)d_in[0];
  const float* attn_mask = (const float*)d_in[1];
  const int* input_ids = (const int*)d_in[2];
  const float* sparse_W = (const float*)d_in[3];
  const float* sparse_b = (const float*)d_in[4];
  const float* colbert_W = (const float*)d_in[5];
  const float* colbert_b = (const float*)d_in[6];
  float* out = (float*)d_out;

  unsigned short* Wt = (unsigned short*)d_ws;   // 2 MiB packed bf16 weights

  prep_kernel<<<1552, 256, 0, stream>>>(colbert_W, Wt, out, hidden);
  fused_kernel<<<M_TOT / 64, 512, FUSED_LDS, stream>>>(
      hidden, Wt, colbert_b, attn_mask, sparse_W, sparse_b, input_ids, out);
}